// Round 11
// baseline (1079.853 us; speedup 1.0000x reference)
//
#include <hip/hip_runtime.h>

#define NCLS 1000
#define DIM 256
#define GCAP 500
#define NT16 64                    // 64 tiles of 16 cols over 1024 padded cols
#define SCLF 20.609930f            // 1/(0.07*ln2)
#define CP 23.0f
#define CPLN2 15.94238515f         // 23*ln2
#define LN2 0.69314718056f
#define PADC 2.86102294921875e-06f // 24 * 2^-23 (pad-column contribution)

typedef __attribute__((ext_vector_type(8))) short short8;
typedef __attribute__((ext_vector_type(4))) float f32x4;

__device__ __forceinline__ short f2bf(float f) {
  unsigned u = __float_as_uint(f);
  unsigned r = u + 0x7fffu + ((u >> 16) & 1u);
  return (short)(r >> 16);
}
__device__ __forceinline__ float bf2f(short s) {
  unsigned u = ((unsigned)(unsigned short)s) << 16;
  return __uint_as_float(u);
}
__device__ __forceinline__ float fexp2(float x) {
#if __has_builtin(__builtin_amdgcn_exp2f)
  return __builtin_amdgcn_exp2f(x);
#else
  return exp2f(x);
#endif
}
__device__ __forceinline__ void gload_lds16(const void* g, void* l) {
  __builtin_amdgcn_global_load_lds(
      (const __attribute__((address_space(1))) unsigned int*)g,
      (__attribute__((address_space(3))) unsigned int*)l, 16, 0, 0);
}

// ---------------- K0: scatter rows into per-class lists ------------------------
__global__ __launch_bounds__(256) void scatter_kernel(
    const int* __restrict__ sl, const int* __restrict__ tl, int N,
    int* __restrict__ gcnt, int* __restrict__ glist) {
  const int i = blockIdx.x * 256 + threadIdx.x;
  if (i >= 2 * N) return;
  const int side = (i >= N) ? 1 : 0;
  const int r = i - side * N;
  const int c = (side ? tl : sl)[r];
  const int bin = side * NCLS + c;
  const int slot = atomicAdd(gcnt + bin, 1);
  if (slot < GCAP) glist[(size_t)bin * GCAP + slot] = r;
}

// ---------------- K1: per-class gather + mean + normalize ----------------------
__global__ __launch_bounds__(256) void proto_kernel(
    const float* __restrict__ sf, const float* __restrict__ tf,
    const int* __restrict__ gcnt, const int* __restrict__ glist,
    float* __restrict__ mean_out, float* __restrict__ spn, float* __restrict__ tpn,
    unsigned short* __restrict__ pbf) {
  const int bid = blockIdx.x;
  const int side = (bid >= NCLS) ? 1 : 0;
  const int c = bid - side * NCLS;
  const float* feats = side ? tf : sf;
  const int* list = glist + (size_t)bid * GCAP;
  const int m = min(gcnt[bid], GCAP);
  const int t = threadIdx.x;
  __shared__ float s_red[4];

  float a0 = 0.f, a1 = 0.f, a2 = 0.f, a3 = 0.f, a4 = 0.f, a5 = 0.f, a6 = 0.f, a7 = 0.f;
  int i = 0;
  for (; i + 8 <= m; i += 8) {
    a0 += feats[(size_t)list[i + 0] * DIM + t];
    a1 += feats[(size_t)list[i + 1] * DIM + t];
    a2 += feats[(size_t)list[i + 2] * DIM + t];
    a3 += feats[(size_t)list[i + 3] * DIM + t];
    a4 += feats[(size_t)list[i + 4] * DIM + t];
    a5 += feats[(size_t)list[i + 5] * DIM + t];
    a6 += feats[(size_t)list[i + 6] * DIM + t];
    a7 += feats[(size_t)list[i + 7] * DIM + t];
  }
  for (; i < m; i++) a0 += feats[(size_t)list[i] * DIM + t];
  const float sum = ((a0 + a1) + (a2 + a3)) + ((a4 + a5) + (a6 + a7));
  const float mean = sum / fmaxf((float)m, 1.0f);
  if (!side) mean_out[(size_t)c * DIM + t] = mean;

  float ss = mean * mean;
  #pragma unroll
  for (int o = 1; o < 64; o <<= 1) ss += __shfl_xor(ss, o);
  if ((t & 63) == 0) s_red[t >> 6] = ss;
  __syncthreads();
  const float tot = s_red[0] + s_red[1] + s_red[2] + s_red[3];
  const float innv = 1.0f / fmaxf(sqrtf(tot), 1e-12f);
  const float p = mean * innv;
  (side ? tpn : spn)[(size_t)c * DIM + t] = p;
  if (!side) {
    // tiled bf16 layout: [c>>4][kf=t>>5][lg=(t>>3)&3][c&15][e=t&7]
    size_t off = (size_t)(c >> 4) * 4096 + (size_t)(t >> 5) * 512
               + (size_t)((t >> 3) & 3) * 128 + (size_t)(c & 15) * 8 + (t & 7);
    pbf[off] = (unsigned short)f2bf(p);
  }
}

// ---------------- K2: structure matrices + struct loss (fp32, 64x64 tiles) -----
__global__ __launch_bounds__(256) void struct_kernel(
    const float* __restrict__ spn, const float* __restrict__ tpn,
    float* __restrict__ out_struct, float* __restrict__ acc) {
  __shared__ float Sa[16][68], Sb[16][68], Ta[16][68], Tb[16][68];
  __shared__ float red[256];
  const int t = threadIdx.x;
  const int tx = t & 15, ty = t >> 4;
  const int i0 = blockIdx.y * 64, j0 = blockIdx.x * 64;
  float cs[4][4], cg[4][4];
  #pragma unroll
  for (int a = 0; a < 4; a++)
    #pragma unroll
    for (int b = 0; b < 4; b++) { cs[a][b] = 0.f; cg[a][b] = 0.f; }

  const int srow = t >> 2;
  const int skq = (t & 3) * 4;
  for (int k0 = 0; k0 < DIM; k0 += 16) {
    __syncthreads();
    {
      float4 z = make_float4(0.f, 0.f, 0.f, 0.f);
      int ra = i0 + srow, rb = j0 + srow;
      float4 va = (ra < NCLS) ? *(const float4*)(spn + (size_t)ra * DIM + k0 + skq) : z;
      float4 vb = (rb < NCLS) ? *(const float4*)(spn + (size_t)rb * DIM + k0 + skq) : z;
      float4 wa = (ra < NCLS) ? *(const float4*)(tpn + (size_t)ra * DIM + k0 + skq) : z;
      float4 wb = (rb < NCLS) ? *(const float4*)(tpn + (size_t)rb * DIM + k0 + skq) : z;
      Sa[skq+0][srow]=va.x; Sa[skq+1][srow]=va.y; Sa[skq+2][srow]=va.z; Sa[skq+3][srow]=va.w;
      Sb[skq+0][srow]=vb.x; Sb[skq+1][srow]=vb.y; Sb[skq+2][srow]=vb.z; Sb[skq+3][srow]=vb.w;
      Ta[skq+0][srow]=wa.x; Ta[skq+1][srow]=wa.y; Ta[skq+2][srow]=wa.z; Ta[skq+3][srow]=wa.w;
      Tb[skq+0][srow]=wb.x; Tb[skq+1][srow]=wb.y; Tb[skq+2][srow]=wb.z; Tb[skq+3][srow]=wb.w;
    }
    __syncthreads();
    #pragma unroll
    for (int k = 0; k < 16; k++) {
      float a[4], b[4], c[4], d[4];
      *(float4*)a = *(const float4*)&Sa[k][ty * 4];
      *(float4*)b = *(const float4*)&Sb[k][tx * 4];
      *(float4*)c = *(const float4*)&Ta[k][ty * 4];
      *(float4*)d = *(const float4*)&Tb[k][tx * 4];
      #pragma unroll
      for (int ii = 0; ii < 4; ii++)
        #pragma unroll
        for (int jj = 0; jj < 4; jj++) {
          cs[ii][jj] = fmaf(a[ii], b[jj], cs[ii][jj]);
          cg[ii][jj] = fmaf(c[ii], d[jj], cg[ii][jj]);
        }
    }
  }
  float d2 = 0.f;
  #pragma unroll
  for (int ii = 0; ii < 4; ii++) {
    int gi = i0 + ty * 4 + ii;
    if (gi < NCLS) {
      #pragma unroll
      for (int jj = 0; jj < 4; jj++) {
        int gj = j0 + tx * 4 + jj;
        if (gj < NCLS) {
          out_struct[(size_t)gi * NCLS + gj] = cs[ii][jj];
          float df = cs[ii][jj] - cg[ii][jj];
          d2 += df * df;
        }
      }
    }
  }
  red[t] = d2;
  __syncthreads();
  for (int o = 128; o > 0; o >>= 1) { if (t < o) red[t] += red[t + o]; __syncthreads(); }
  if (t == 0) atomicAdd(acc, red[0]);
}

// ------- K3: contrastive loss — wave-private LDS dbuf, ZERO barriers -----------
// 128-thread blocks, 2 waves x 64 rows; each wave stages its own 8KB tile ring;
// sync is wave-local counted vmcnt only. Scale folded into bf16 A; label logit
// via fp32 prologue dot (wpre).
__global__ __launch_bounds__(128, 2) void contrast_kernel(
    const float* __restrict__ feats, const int* __restrict__ labels,
    const float* __restrict__ pn, const unsigned short* __restrict__ pbf,
    float* __restrict__ acc_out, int N) {
  __shared__ __align__(16) unsigned short Bt[2][2][4096];  // [wave][buf][8KB tile]
  const int t = threadIdx.x;
  const int lane = t & 63, wid = t >> 6;
  const int lx = lane & 15, lg = lane >> 4;
  const int rbase = blockIdx.x * 128 + wid * 64;
  const float4 z4 = make_float4(0.f, 0.f, 0.f, 0.f);

  short8 af[4][8];       // 64 rows/wave, SCALED bf16 (logits in ln2 units)
  float sSt[4][4];
  float wpre = 0.f;      // per-lane partial of label logits (ln2 units)

  #pragma unroll
  for (int rf = 0; rf < 4; rf++) {
    const int r = rbase + rf * 16 + lx;
    const bool v = r < N;
    const float* rp = feats + (size_t)r * DIM + (lg << 3);
    float n2 = 0.f;
    #pragma unroll
    for (int kf = 0; kf < 8; kf++) {
      float4 x = v ? *(const float4*)(rp + kf * 32)     : z4;
      float4 y = v ? *(const float4*)(rp + kf * 32 + 4) : z4;
      n2 += x.x*x.x + x.y*x.y + x.z*x.z + x.w*x.w
          + y.x*y.x + y.y*y.y + y.z*y.z + y.w*y.w;
    }
    n2 += __shfl_xor(n2, 16);
    n2 += __shfl_xor(n2, 32);
    const float sw = SCLF / fmaxf(sqrtf(n2), 1e-12f);
    const int lb = v ? labels[r] : 0;
    const float* pp = pn + (size_t)lb * DIM + (lg << 3);
    float pl = 0.f;
    // second pass (L1/L2-hot): fold scale into bf16 A; fp32 label dot
    #pragma unroll
    for (int kf = 0; kf < 8; kf++) {
      float4 x  = v ? *(const float4*)(rp + kf * 32)     : z4;
      float4 y  = v ? *(const float4*)(rp + kf * 32 + 4) : z4;
      float4 px = v ? *(const float4*)(pp + kf * 32)     : z4;
      float4 py = v ? *(const float4*)(pp + kf * 32 + 4) : z4;
      short8 f;
      f[0] = f2bf(x.x * sw); f[1] = f2bf(x.y * sw);
      f[2] = f2bf(x.z * sw); f[3] = f2bf(x.w * sw);
      f[4] = f2bf(y.x * sw); f[5] = f2bf(y.y * sw);
      f[6] = f2bf(y.z * sw); f[7] = f2bf(y.w * sw);
      af[rf][kf] = f;
      pl += bf2f(f[0]) * px.x + bf2f(f[1]) * px.y
          + bf2f(f[2]) * px.z + bf2f(f[3]) * px.w
          + bf2f(f[4]) * py.x + bf2f(f[5]) * py.y
          + bf2f(f[6]) * py.z + bf2f(f[7]) * py.w;
    }
    wpre += pl;
    #pragma unroll
    for (int reg = 0; reg < 4; reg++) sSt[rf][reg] = 0.f;
  }

  unsigned short* lbase = &Bt[wid][0][0];   // wave-uniform LDS base

  // stage tile h_ (8KB) into this wave's buffer b_: 8 x 1KB wave-linear copies
  #define STAGEW(h_, b_)                                                        \
    {                                                                           \
      const unsigned short* g0 = pbf + ((size_t)(h_) << 12) + (lane << 3);      \
      unsigned short* l0 = lbase + ((b_) << 12);                                \
      _Pragma("unroll")                                                         \
      for (int q = 0; q < 8; q++)                                               \
        gload_lds16(g0 + (q << 9), l0 + (q << 9));                              \
    }

  STAGEW(0, 0);

  for (int h = 0; h < NT16; h++) {
    if (h < NT16 - 1) {
      STAGEW(h + 1, (h + 1) & 1);
      asm volatile("s_waitcnt vmcnt(8)" ::: "memory");  // own tile-h loads done
    } else {
      asm volatile("s_waitcnt vmcnt(0)" ::: "memory");
    }
    __builtin_amdgcn_sched_barrier(0);  // keep ds_reads below the counted wait

    const unsigned short* bb = lbase + ((h & 1) << 12) + (lg << 7) + (lx << 3);
    f32x4 d0 = {0.f, 0.f, 0.f, 0.f};
    f32x4 d1 = {0.f, 0.f, 0.f, 0.f};
    f32x4 d2 = {0.f, 0.f, 0.f, 0.f};
    f32x4 d3 = {0.f, 0.f, 0.f, 0.f};
    #pragma unroll
    for (int kf = 0; kf < 8; kf++) {
      short8 b = *(const short8*)(bb + (kf << 9));
      d0 = __builtin_amdgcn_mfma_f32_16x16x32_bf16(af[0][kf], b, d0, 0, 0, 0);
      d1 = __builtin_amdgcn_mfma_f32_16x16x32_bf16(af[1][kf], b, d1, 0, 0, 0);
      d2 = __builtin_amdgcn_mfma_f32_16x16x32_bf16(af[2][kf], b, d2, 0, 0, 0);
      d3 = __builtin_amdgcn_mfma_f32_16x16x32_bf16(af[3][kf], b, d3, 0, 0, 0);
    }
    #pragma unroll
    for (int reg = 0; reg < 4; reg++) {
      sSt[0][reg] += fexp2(d0[reg] - CP);
      sSt[1][reg] += fexp2(d1[reg] - CP);
      sSt[2][reg] += fexp2(d2[reg] - CP);
      sSt[3][reg] += fexp2(d3[reg] - CP);
    }
  }

  float wl = 0.f;
  #pragma unroll
  for (int rf = 0; rf < 4; rf++)
    #pragma unroll
    for (int reg = 0; reg < 4; reg++) {
      float s = sSt[rf][reg];
      #pragma unroll
      for (int o = 1; o < 16; o <<= 1) s += __shfl_xor(s, o);
      const int row = rbase + rf * 16 + (lg << 2) + reg;
      if (lx == 0 && row < N) wl += logf(s - PADC) + CPLN2;
    }

  // per-wave reduction: contrib nonzero on lx==0 lanes (wl) + all lanes (wpre)
  float contrib = wl - wpre * LN2;
  #pragma unroll
  for (int o = 1; o < 64; o <<= 1) contrib += __shfl_xor(contrib, o);
  if (lane == 0) atomicAdd(acc_out, contrib);
}

// ---------------- K4: scalars ---------------------------------------------------
__global__ void final_kernel(const float* __restrict__ acc, float* __restrict__ out, int N) {
  out[0] = acc[0] * (1.0f / (float)(NCLS * NCLS));
  out[1] = acc[1] / (float)N;
}

extern "C" void kernel_launch(void* const* d_in, const int* in_sizes, int n_in,
                              void* d_out, int out_size, void* d_ws, size_t ws_size,
                              hipStream_t stream) {
  const float* src_feats  = (const float*)d_in[0];
  const int*   src_labels = (const int*)d_in[1];
  const float* tgt_feats  = (const float*)d_in[2];
  const int*   tgt_labels = (const int*)d_in[3];
  const int N = in_sizes[0] / DIM;

  // ws layout (floats):
  // [0,16)           acc: [0]=struct sq-sum, [1]=contrast sum
  // [16,256016)      src_pn
  // [256016,512016)  tgt_pn
  // [512016,643088)  pbf: 64 tiles x 4096 ushorts (1024 padded cols)
  // [643088,645088)  gcnt: 2000 ints
  float* ws = (float*)d_ws;
  float* acc    = ws;
  float* src_pn = ws + 16;
  float* tgt_pn = ws + 256016;
  unsigned short* pbf = (unsigned short*)(ws + 512016);
  int* gcnt = (int*)(ws + 643088);

  float* out_f      = (float*)d_out;
  float* out_protos = out_f + 2;
  float* out_struct = out_f + 2 + NCLS * DIM;
  // glist borrows the out_struct region (1M ints); struct_kernel overwrites it later
  int* glist = (int*)out_struct;

  hipMemsetAsync(acc, 0, 2 * sizeof(float), stream);
  hipMemsetAsync(gcnt, 0, 2 * NCLS * sizeof(int), stream);
  hipMemsetAsync(pbf + 62 * 4096, 0, 2 * 4096 * sizeof(unsigned short), stream);

  int sblocks = (2 * N + 255) / 256;
  scatter_kernel<<<sblocks, 256, 0, stream>>>(src_labels, tgt_labels, N, gcnt, glist);

  proto_kernel<<<2 * NCLS, 256, 0, stream>>>(src_feats, tgt_feats, gcnt, glist,
                                             out_protos, src_pn, tgt_pn, pbf);

  dim3 sgrid(16, 16);
  struct_kernel<<<sgrid, 256, 0, stream>>>(src_pn, tgt_pn, out_struct, acc);

  int cblocks = (N + 127) / 128;
  contrast_kernel<<<cblocks, 128, 0, stream>>>(src_feats, src_labels, src_pn, pbf,
                                               acc + 1, N);

  final_kernel<<<1, 1, 0, stream>>>(acc, out_f, N);
}

// Round 12
// 631.277 us; speedup vs baseline: 1.7106x; 1.7106x over previous
//
#include <hip/hip_runtime.h>
#include <hip/hip_fp8.h>

#define NCLS 1000
#define DIM 256
#define GCAP 500
#define NT16 64                    // 64 tiles of 16 cols over 1024 padded cols
#define SCLF 20.609930f            // 1/(0.07*ln2)
#define CP 23.0f
#define CPLN2 15.94238515f         // 23*ln2
#define LN2 0.69314718056f
#define PADC 2.86102294921875e-06f // 24 * 2^-23 (pad-column contribution)

typedef __attribute__((ext_vector_type(4))) float f32x4;
typedef long long i64;

#if defined(__has_builtin) && __has_builtin(__builtin_amdgcn_cvt_pk_fp8_f32)
#define CVTPK(a, b, old, hi) __builtin_amdgcn_cvt_pk_fp8_f32((a), (b), (old), (hi))
#else
__device__ __forceinline__ unsigned cvtpk_sw(float a, float b, unsigned old, bool hi) {
  unsigned lo8 = __hip_cvt_float_to_fp8(a, __HIP_SATFINITE, __HIP_E4M3);
  unsigned hi8 = __hip_cvt_float_to_fp8(b, __HIP_SATFINITE, __HIP_E4M3);
  unsigned pk = lo8 | (hi8 << 8);
  return hi ? ((old & 0xffffu) | (pk << 16)) : ((old & 0xffff0000u) | pk);
}
#define CVTPK(a, b, old, hi) cvtpk_sw((a), (b), (old), (hi))
#endif

__device__ __forceinline__ float fexp2(float x) {
#if __has_builtin(__builtin_amdgcn_exp2f)
  return __builtin_amdgcn_exp2f(x);
#else
  return exp2f(x);
#endif
}

// ---------------- K0: scatter rows into per-class lists ------------------------
__global__ __launch_bounds__(256) void scatter_kernel(
    const int* __restrict__ sl, const int* __restrict__ tl, int N,
    int* __restrict__ gcnt, int* __restrict__ glist) {
  const int i = blockIdx.x * 256 + threadIdx.x;
  if (i >= 2 * N) return;
  const int side = (i >= N) ? 1 : 0;
  const int r = i - side * N;
  const int c = (side ? tl : sl)[r];
  const int bin = side * NCLS + c;
  const int slot = atomicAdd(gcnt + bin, 1);
  if (slot < GCAP) glist[(size_t)bin * GCAP + slot] = r;
}

// ---------------- K1: per-class gather + mean + normalize ----------------------
__global__ __launch_bounds__(256) void proto_kernel(
    const float* __restrict__ sf, const float* __restrict__ tf,
    const int* __restrict__ gcnt, const int* __restrict__ glist,
    float* __restrict__ mean_out, float* __restrict__ spn, float* __restrict__ tpn,
    unsigned char* __restrict__ pbf8) {
  const int bid = blockIdx.x;
  const int side = (bid >= NCLS) ? 1 : 0;
  const int c = bid - side * NCLS;
  const float* feats = side ? tf : sf;
  const int* list = glist + (size_t)bid * GCAP;
  const int m = min(gcnt[bid], GCAP);
  const int t = threadIdx.x;
  __shared__ float s_red[4];

  float a0 = 0.f, a1 = 0.f, a2 = 0.f, a3 = 0.f, a4 = 0.f, a5 = 0.f, a6 = 0.f, a7 = 0.f;
  int i = 0;
  for (; i + 8 <= m; i += 8) {
    a0 += feats[(size_t)list[i + 0] * DIM + t];
    a1 += feats[(size_t)list[i + 1] * DIM + t];
    a2 += feats[(size_t)list[i + 2] * DIM + t];
    a3 += feats[(size_t)list[i + 3] * DIM + t];
    a4 += feats[(size_t)list[i + 4] * DIM + t];
    a5 += feats[(size_t)list[i + 5] * DIM + t];
    a6 += feats[(size_t)list[i + 6] * DIM + t];
    a7 += feats[(size_t)list[i + 7] * DIM + t];
  }
  for (; i < m; i++) a0 += feats[(size_t)list[i] * DIM + t];
  const float sum = ((a0 + a1) + (a2 + a3)) + ((a4 + a5) + (a6 + a7));
  const float mean = sum / fmaxf((float)m, 1.0f);
  if (!side) mean_out[(size_t)c * DIM + t] = mean;

  float ss = mean * mean;
  #pragma unroll
  for (int o = 1; o < 64; o <<= 1) ss += __shfl_xor(ss, o);
  if ((t & 63) == 0) s_red[t >> 6] = ss;
  __syncthreads();
  const float tot = s_red[0] + s_red[1] + s_red[2] + s_red[3];
  const float innv = 1.0f / fmaxf(sqrtf(tot), 1e-12f);
  const float p = mean * innv;
  (side ? tpn : spn)[(size_t)c * DIM + t] = p;
  if (!side) {
    // fp8 tiled layout: [c>>4][kf2=t>>6][lg=(t>>3)&3][c&15][odd=(t>>5)&1][e=t&7]
    size_t off = (size_t)(c >> 4) * 4096 + (size_t)(t >> 6) * 1024
               + (size_t)((t >> 3) & 3) * 256 + (size_t)(c & 15) * 16
               + (size_t)((t >> 5) & 1) * 8 + (t & 7);
    unsigned q = CVTPK(p, p, 0u, false);
    pbf8[off] = (unsigned char)(q & 0xffu);
  }
}

// ---------------- K2: structure matrices + struct loss (fp32, 64x64 tiles) -----
__global__ __launch_bounds__(256) void struct_kernel(
    const float* __restrict__ spn, const float* __restrict__ tpn,
    float* __restrict__ out_struct, float* __restrict__ acc) {
  __shared__ float Sa[16][68], Sb[16][68], Ta[16][68], Tb[16][68];
  __shared__ float red[256];
  const int t = threadIdx.x;
  const int tx = t & 15, ty = t >> 4;
  const int i0 = blockIdx.y * 64, j0 = blockIdx.x * 64;
  float cs[4][4], cg[4][4];
  #pragma unroll
  for (int a = 0; a < 4; a++)
    #pragma unroll
    for (int b = 0; b < 4; b++) { cs[a][b] = 0.f; cg[a][b] = 0.f; }

  const int srow = t >> 2;
  const int skq = (t & 3) * 4;
  for (int k0 = 0; k0 < DIM; k0 += 16) {
    __syncthreads();
    {
      float4 z = make_float4(0.f, 0.f, 0.f, 0.f);
      int ra = i0 + srow, rb = j0 + srow;
      float4 va = (ra < NCLS) ? *(const float4*)(spn + (size_t)ra * DIM + k0 + skq) : z;
      float4 vb = (rb < NCLS) ? *(const float4*)(spn + (size_t)rb * DIM + k0 + skq) : z;
      float4 wa = (ra < NCLS) ? *(const float4*)(tpn + (size_t)ra * DIM + k0 + skq) : z;
      float4 wb = (rb < NCLS) ? *(const float4*)(tpn + (size_t)rb * DIM + k0 + skq) : z;
      Sa[skq+0][srow]=va.x; Sa[skq+1][srow]=va.y; Sa[skq+2][srow]=va.z; Sa[skq+3][srow]=va.w;
      Sb[skq+0][srow]=vb.x; Sb[skq+1][srow]=vb.y; Sb[skq+2][srow]=vb.z; Sb[skq+3][srow]=vb.w;
      Ta[skq+0][srow]=wa.x; Ta[skq+1][srow]=wa.y; Ta[skq+2][srow]=wa.z; Ta[skq+3][srow]=wa.w;
      Tb[skq+0][srow]=wb.x; Tb[skq+1][srow]=wb.y; Tb[skq+2][srow]=wb.z; Tb[skq+3][srow]=wb.w;
    }
    __syncthreads();
    #pragma unroll
    for (int k = 0; k < 16; k++) {
      float a[4], b[4], c[4], d[4];
      *(float4*)a = *(const float4*)&Sa[k][ty * 4];
      *(float4*)b = *(const float4*)&Sb[k][tx * 4];
      *(float4*)c = *(const float4*)&Ta[k][ty * 4];
      *(float4*)d = *(const float4*)&Tb[k][tx * 4];
      #pragma unroll
      for (int ii = 0; ii < 4; ii++)
        #pragma unroll
        for (int jj = 0; jj < 4; jj++) {
          cs[ii][jj] = fmaf(a[ii], b[jj], cs[ii][jj]);
          cg[ii][jj] = fmaf(c[ii], d[jj], cg[ii][jj]);
        }
    }
  }
  float d2 = 0.f;
  #pragma unroll
  for (int ii = 0; ii < 4; ii++) {
    int gi = i0 + ty * 4 + ii;
    if (gi < NCLS) {
      #pragma unroll
      for (int jj = 0; jj < 4; jj++) {
        int gj = j0 + tx * 4 + jj;
        if (gj < NCLS) {
          out_struct[(size_t)gi * NCLS + gj] = cs[ii][jj];
          float df = cs[ii][jj] - cg[ii][jj];
          d2 += df * df;
        }
      }
    }
  }
  red[t] = d2;
  __syncthreads();
  for (int o = 128; o > 0; o >>= 1) { if (t < o) red[t] += red[t + o]; __syncthreads(); }
  if (t == 0) atomicAdd(acc, red[0]);
}

// ------- K3: contrastive loss — fp8 MFMA, register-dbuf B, NO LDS staging ------
// 4 waves x 32 rows, wave-private everything, no barriers in main loop; label
// logit via fp32 prologue dot (wpre); loss = LSE - label.
__global__ __launch_bounds__(256, 2) void contrast_kernel(
    const float* __restrict__ feats, const int* __restrict__ labels,
    const float* __restrict__ pn, const unsigned char* __restrict__ pbf8,
    float* __restrict__ acc_out, int N) {
  __shared__ float red[256];
  const int t = threadIdx.x;
  const int lane = t & 63, w = t >> 6;
  const int lx = lane & 15, lg = lane >> 4;
  const int row0 = blockIdx.x * 128 + w * 32;
  const float4 z4 = make_float4(0.f, 0.f, 0.f, 0.f);

  i64 af[2][8];          // 32 rows/wave, raw feats in e4m3 (8 bytes per kf)
  float sclF[2][4];      // (1/(T*ln2))/||f|| per owned row
  float sSt[2][4];
  float wpre = 0.f;      // per-lane partial: (label raw dot) * sw

  #pragma unroll
  for (int rf = 0; rf < 2; rf++) {
    const int r = row0 + rf * 16 + lx;
    const bool v = r < N;
    const float* rp = feats + (size_t)r * DIM + (lg << 3);
    const int lb = v ? labels[r] : 0;
    const float* pp = pn + (size_t)lb * DIM + (lg << 3);
    float n2 = 0.f, pl = 0.f;
    #pragma unroll
    for (int kf = 0; kf < 8; kf++) {
      float4 x  = v ? *(const float4*)(rp + kf * 32)     : z4;
      float4 y  = v ? *(const float4*)(rp + kf * 32 + 4) : z4;
      float4 px = v ? *(const float4*)(pp + kf * 32)     : z4;
      float4 py = v ? *(const float4*)(pp + kf * 32 + 4) : z4;
      n2 += x.x*x.x + x.y*x.y + x.z*x.z + x.w*x.w
          + y.x*y.x + y.y*y.y + y.z*y.z + y.w*y.w;
      pl += x.x*px.x + x.y*px.y + x.z*px.z + x.w*px.w
          + y.x*py.x + y.y*py.y + y.z*py.z + y.w*py.w;
      unsigned w0 = CVTPK(x.x, x.y, 0u, false);
      w0 = CVTPK(x.z, x.w, w0, true);
      unsigned w1 = CVTPK(y.x, y.y, 0u, false);
      w1 = CVTPK(y.z, y.w, w1, true);
      af[rf][kf] = (i64)(((unsigned long long)w1 << 32) | (unsigned long long)w0);
    }
    n2 += __shfl_xor(n2, 16);
    n2 += __shfl_xor(n2, 32);
    const float sw = SCLF / fmaxf(sqrtf(n2), 1e-12f);
    wpre += pl * sw;
    #pragma unroll
    for (int reg = 0; reg < 4; reg++) {
      sclF[rf][reg] = __shfl(sw, (lg << 2) | reg);
      sSt[rf][reg] = 0.f;
    }
  }

  // B fragments direct from L2: per tile cf, 4 x int4 (kf-pairs), wave-private
  const unsigned char* bbase = pbf8 + (lg << 8) + (lx << 4);
  int4 bA[4], bB[4];

  #define LOADB(dst_, cf_)                                                      \
    {                                                                           \
      const int4* gp = (const int4*)(bbase + ((size_t)(cf_) << 12));            \
      _Pragma("unroll")                                                         \
      for (int q = 0; q < 4; q++) dst_[q] = gp[q << 6];                         \
    }

  #define COMPUTE(buf_)                                                         \
    {                                                                           \
      f32x4 d0 = {0.f, 0.f, 0.f, 0.f};                                          \
      f32x4 d1 = {0.f, 0.f, 0.f, 0.f};                                          \
      _Pragma("unroll")                                                         \
      for (int q = 0; q < 4; q++) {                                             \
        i64 b0 = ((const i64*)&buf_[q])[0];                                     \
        i64 b1 = ((const i64*)&buf_[q])[1];                                     \
        d0 = __builtin_amdgcn_mfma_f32_16x16x32_fp8_fp8(af[0][2*q],   b0, d0, 0, 0, 0); \
        d1 = __builtin_amdgcn_mfma_f32_16x16x32_fp8_fp8(af[1][2*q],   b0, d1, 0, 0, 0); \
        d0 = __builtin_amdgcn_mfma_f32_16x16x32_fp8_fp8(af[0][2*q+1], b1, d0, 0, 0, 0); \
        d1 = __builtin_amdgcn_mfma_f32_16x16x32_fp8_fp8(af[1][2*q+1], b1, d1, 0, 0, 0); \
      }                                                                         \
      _Pragma("unroll")                                                         \
      for (int reg = 0; reg < 4; reg++) {                                       \
        sSt[0][reg] += fexp2(fmaf(d0[reg], sclF[0][reg], -CP));                 \
        sSt[1][reg] += fexp2(fmaf(d1[reg], sclF[1][reg], -CP));                 \
      }                                                                         \
    }

  LOADB(bA, 0);
  for (int cf = 0; cf < NT16; cf += 2) {
    LOADB(bB, cf + 1);
    COMPUTE(bA);
    if (cf + 2 < NT16) LOADB(bA, cf + 2);
    COMPUTE(bB);
  }

  float wl = 0.f;
  #pragma unroll
  for (int rf = 0; rf < 2; rf++)
    #pragma unroll
    for (int reg = 0; reg < 4; reg++) {
      float s = sSt[rf][reg];
      #pragma unroll
      for (int o = 1; o < 16; o <<= 1) s += __shfl_xor(s, o);
      const int row = row0 + rf * 16 + (lg << 2) + reg;
      if (lx == 0 && row < N) wl += logf(s - PADC) + CPLN2;
    }

  red[t] = wl - wpre * LN2;
  __syncthreads();
  for (int o = 128; o > 0; o >>= 1) { if (t < o) red[t] += red[t + o]; __syncthreads(); }
  if (t == 0) atomicAdd(acc_out, red[0]);
}

// ---------------- K4: scalars ---------------------------------------------------
__global__ void final_kernel(const float* __restrict__ acc, float* __restrict__ out, int N) {
  out[0] = acc[0] * (1.0f / (float)(NCLS * NCLS));
  out[1] = acc[1] / (float)N;
}

extern "C" void kernel_launch(void* const* d_in, const int* in_sizes, int n_in,
                              void* d_out, int out_size, void* d_ws, size_t ws_size,
                              hipStream_t stream) {
  const float* src_feats  = (const float*)d_in[0];
  const int*   src_labels = (const int*)d_in[1];
  const float* tgt_feats  = (const float*)d_in[2];
  const int*   tgt_labels = (const int*)d_in[3];
  const int N = in_sizes[0] / DIM;

  // ws layout (floats):
  // [0,16)           acc: [0]=struct sq-sum, [1]=contrast sum
  // [16,256016)      src_pn
  // [256016,512016)  tgt_pn
  // [512016,577552)  pbf8: 64 tiles x 4096 bytes (fp8 e4m3, 1024 padded cols)
  // [643088,645088)  gcnt: 2000 ints
  float* ws = (float*)d_ws;
  float* acc    = ws;
  float* src_pn = ws + 16;
  float* tgt_pn = ws + 256016;
  unsigned char* pbf8 = (unsigned char*)(ws + 512016);
  int* gcnt = (int*)(ws + 643088);

  float* out_f      = (float*)d_out;
  float* out_protos = out_f + 2;
  float* out_struct = out_f + 2 + NCLS * DIM;
  // glist borrows the out_struct region (1M ints); struct_kernel overwrites it later
  int* glist = (int*)out_struct;

  hipMemsetAsync(acc, 0, 2 * sizeof(float), stream);
  hipMemsetAsync(gcnt, 0, 2 * NCLS * sizeof(int), stream);
  hipMemsetAsync(pbf8 + 62 * 4096, 0, 2 * 4096, stream);

  int sblocks = (2 * N + 255) / 256;
  scatter_kernel<<<sblocks, 256, 0, stream>>>(src_labels, tgt_labels, N, gcnt, glist);

  proto_kernel<<<2 * NCLS, 256, 0, stream>>>(src_feats, tgt_feats, gcnt, glist,
                                             out_protos, src_pn, tgt_pn, pbf8);

  dim3 sgrid(16, 16);
  struct_kernel<<<sgrid, 256, 0, stream>>>(src_pn, tgt_pn, out_struct, acc);

  int cblocks = (N + 127) / 128;
  contrast_kernel<<<cblocks, 256, 0, stream>>>(src_feats, src_labels, src_pn, pbf8,
                                               acc + 1, N);

  final_kernel<<<1, 1, 0, stream>>>(acc, out_f, N);
}